// Round 1
// baseline (603.731 us; speedup 1.0000x reference)
//
#include <hip/hip_runtime.h>

#define H 128

// ---------- helpers ----------
__device__ __forceinline__ void fma4(float4& acc, float s, const float4& b) {
    acc.x += s * b.x; acc.y += s * b.y; acc.z += s * b.z; acc.w += s * b.w;
}

// monotonic float->uint encoding: order-preserving, enc==0 only for 0xFFFFFFFF (-NaN) = sentinel
__device__ __forceinline__ unsigned enc_f(float v) {
    unsigned bits = __float_as_uint(v);
    return bits ^ ((unsigned)((int)bits >> 31) | 0x80000000u);
}
__device__ __forceinline__ float dec_f(unsigned e) {
    unsigned bits = (e & 0x80000000u) ? (e ^ 0x80000000u) : ~e;
    return __uint_as_float(bits);
}

// ---------- kernel 1: ZS = z @ Wmsg[0:128], ZD = z @ Wmsg[128:256] (no bias) ----------
// grid (ceil(N/64), 2), block 256. BM=64 rows x 128 cols per block, 8x4 micro-tile/thread.
__global__ __launch_bounds__(256) void gemm_zszd(
    const float* __restrict__ z, const float* __restrict__ Wmsg,
    float* __restrict__ ZS, float* __restrict__ ZD, int N)
{
    __shared__ float At[64][132];  // +4 pad
    const int half = blockIdx.y;
    const float* B = Wmsg + (size_t)half * H * H;   // [k][c], row stride 128
    float* Out = half ? ZD : ZS;
    const int row0 = blockIdx.x * 64;
    const int t = threadIdx.x;

    // load A tile: 64x128 = 2048 float4, 8 per thread
#pragma unroll
    for (int i = 0; i < 8; ++i) {
        int l = t + i * 256;
        int r = l >> 5, c4 = l & 31;
        int gr = row0 + r;
        float4 v = make_float4(0.f, 0.f, 0.f, 0.f);
        if (gr < N) v = ((const float4*)(z + (size_t)gr * H))[c4];
        *(float4*)&At[r][c4 * 4] = v;
    }
    __syncthreads();

    const int tx = t & 31;   // cols tx*4 .. tx*4+3
    const int ty = t >> 5;   // rows ty*8 .. ty*8+7
    float4 acc[8];
#pragma unroll
    for (int r = 0; r < 8; ++r) acc[r] = make_float4(0.f, 0.f, 0.f, 0.f);

    for (int k = 0; k < H; k += 4) {
        float4 b0 = ((const float4*)(B + (size_t)(k + 0) * H))[tx];
        float4 b1 = ((const float4*)(B + (size_t)(k + 1) * H))[tx];
        float4 b2 = ((const float4*)(B + (size_t)(k + 2) * H))[tx];
        float4 b3 = ((const float4*)(B + (size_t)(k + 3) * H))[tx];
#pragma unroll
        for (int r = 0; r < 8; ++r) {
            float4 a = *(const float4*)&At[ty * 8 + r][k];
            fma4(acc[r], a.x, b0);
            fma4(acc[r], a.y, b1);
            fma4(acc[r], a.z, b2);
            fma4(acc[r], a.w, b3);
        }
    }
#pragma unroll
    for (int r = 0; r < 8; ++r) {
        int gr = row0 + ty * 8 + r;
        if (gr < N) *(float4*)(Out + (size_t)gr * H + tx * 4) = acc[r];
    }
}

// ---------- kernel 2: per-edge scatter-max of encoded (ZS[src] + w*wrow) into Menc[dst] ----------
__global__ __launch_bounds__(256) void edge_max(
    const float4* __restrict__ ZS4, const int* __restrict__ src,
    const int* __restrict__ dst, const float* __restrict__ wgt,
    const float4* __restrict__ wrow4, unsigned* __restrict__ Menc, int total)
{
    int idx = blockIdx.x * blockDim.x + threadIdx.x;
    const int stride = gridDim.x * blockDim.x;
    for (; idx < total; idx += stride) {
        const int e = idx >> 5, c4 = idx & 31;
        const int s = src[e], d = dst[e];
        const float w = wgt[e];
        float4 a = ZS4[(size_t)s * 32 + c4];
        float4 wr = wrow4[c4];
        unsigned e0 = enc_f(a.x + w * wr.x);
        unsigned e1 = enc_f(a.y + w * wr.y);
        unsigned e2 = enc_f(a.z + w * wr.z);
        unsigned e3 = enc_f(a.w + w * wr.w);
        unsigned* p = Menc + ((size_t)d << 7) + (c4 << 2);
        // racy pre-check is safe: M is monotone non-decreasing, stale reads only under-report
        uint4 cur = *(const uint4*)p;
        if (e0 > cur.x) atomicMax(p + 0, e0);
        if (e1 > cur.y) atomicMax(p + 1, e1);
        if (e2 > cur.z) atomicMax(p + 2, e2);
        if (e3 > cur.w) atomicMax(p + 3, e3);
    }
}

// ---------- kernel 3: in-place finalize agg = valid ? M + ZD + b_msg : 0 ----------
__global__ __launch_bounds__(256) void finalize_agg(
    unsigned* __restrict__ Menc, const float4* __restrict__ ZD4,
    const float4* __restrict__ bmsg4, int total4)
{
    int i = blockIdx.x * blockDim.x + threadIdx.x;
    if (i >= total4) return;
    uint4 e = ((const uint4*)Menc)[i];
    float4 zd = ZD4[i];
    float4 bm = bmsg4[i & 31];
    float4 r;
    r.x = (e.x == 0u) ? 0.f : dec_f(e.x) + zd.x + bm.x;
    r.y = (e.y == 0u) ? 0.f : dec_f(e.y) + zd.y + bm.y;
    r.z = (e.z == 0u) ? 0.f : dec_f(e.z) + zd.z + bm.z;
    r.w = (e.w == 0u) ? 0.f : dec_f(e.w) + zd.w + bm.w;
    ((float4*)Menc)[i] = r;
}

// ---------- kernel 4: out = [z | agg] @ Wupd + bupd ----------
// grid ceil(N/32), block 256. BM=32 rows x 128 cols, 4x4 micro-tile/thread, K=256.
__global__ __launch_bounds__(256) void gemm_upd(
    const float* __restrict__ z, const float* __restrict__ agg,
    const float* __restrict__ Wupd, const float* __restrict__ bupd,
    float* __restrict__ out, int N)
{
    __shared__ float At[32][260];  // 32 x 256 + pad
    const int row0 = blockIdx.x * 32;
    const int t = threadIdx.x;

    // load A tile: 32 rows x 256 cols = 2048 float4, 8 per thread
#pragma unroll
    for (int i = 0; i < 8; ++i) {
        int l = t + i * 256;
        int r = l >> 6, c4 = l & 63;
        int gr = row0 + r;
        float4 v = make_float4(0.f, 0.f, 0.f, 0.f);
        if (gr < N) {
            if (c4 < 32) v = ((const float4*)(z + (size_t)gr * H))[c4];
            else         v = ((const float4*)(agg + (size_t)gr * H))[c4 - 32];
        }
        *(float4*)&At[r][c4 * 4] = v;
    }
    __syncthreads();

    const int tx = t & 31;   // cols tx*4..+3
    const int ty = t >> 5;   // rows ty*4..+3
    float4 acc[4];
#pragma unroll
    for (int r = 0; r < 4; ++r) acc[r] = make_float4(0.f, 0.f, 0.f, 0.f);

    for (int k = 0; k < 2 * H; k += 4) {
        float4 b0 = ((const float4*)(Wupd + (size_t)(k + 0) * H))[tx];
        float4 b1 = ((const float4*)(Wupd + (size_t)(k + 1) * H))[tx];
        float4 b2 = ((const float4*)(Wupd + (size_t)(k + 2) * H))[tx];
        float4 b3 = ((const float4*)(Wupd + (size_t)(k + 3) * H))[tx];
#pragma unroll
        for (int r = 0; r < 4; ++r) {
            float4 a = *(const float4*)&At[ty * 4 + r][k];
            fma4(acc[r], a.x, b0);
            fma4(acc[r], a.y, b1);
            fma4(acc[r], a.z, b2);
            fma4(acc[r], a.w, b3);
        }
    }
    float4 bias = ((const float4*)bupd)[tx];
#pragma unroll
    for (int r = 0; r < 4; ++r) {
        int gr = row0 + ty * 4 + r;
        if (gr < N) {
            acc[r].x += bias.x; acc[r].y += bias.y; acc[r].z += bias.z; acc[r].w += bias.w;
            *(float4*)(out + (size_t)gr * H + tx * 4) = acc[r];
        }
    }
}

extern "C" void kernel_launch(void* const* d_in, const int* in_sizes, int n_in,
                              void* d_out, int out_size, void* d_ws, size_t ws_size,
                              hipStream_t stream) {
    const float* z    = (const float*)d_in[0];   // [N,128]
    const int*   src  = (const int*)d_in[1];     // [E]
    const int*   dst  = (const int*)d_in[2];     // [E]
    const float* wgt  = (const float*)d_in[3];   // [E,1]
    const float* Wmsg = (const float*)d_in[4];   // [257,128]
    const float* bmsg = (const float*)d_in[5];   // [128]
    const float* Wupd = (const float*)d_in[6];   // [256,128]
    const float* bupd = (const float*)d_in[7];   // [128]
    float* out = (float*)d_out;

    const int N = in_sizes[0] / H;   // 50000
    const int E = in_sizes[1];       // 640000

    float*    ZS   = (float*)d_ws;
    float*    ZD   = ZS + (size_t)N * H;
    unsigned* Menc = (unsigned*)(ZD + (size_t)N * H);

    // M sentinel: enc 0 decodes to -NaN, below every real value; also the "empty" flag
    hipMemsetAsync(Menc, 0, (size_t)N * H * sizeof(unsigned), stream);

    gemm_zszd<<<dim3((N + 63) / 64, 2), 256, 0, stream>>>(z, Wmsg, ZS, ZD, N);

    const int totalE4 = E * 32;  // E * (128/4)
    edge_max<<<2048, 256, 0, stream>>>((const float4*)ZS, src, dst, wgt,
                                       (const float4*)(Wmsg + (size_t)256 * H),
                                       Menc, totalE4);

    const int totalN4 = N * 32;
    finalize_agg<<<(totalN4 + 255) / 256, 256, 0, stream>>>(
        Menc, (const float4*)ZD, (const float4*)bmsg, totalN4);

    gemm_upd<<<(N + 31) / 32, 256, 0, stream>>>(z, (const float*)Menc, Wupd, bupd, out, N);
}

// Round 2
// 255.113 us; speedup vs baseline: 2.3665x; 2.3665x over previous
//
#include <hip/hip_runtime.h>

#define H 128

// ---------- helpers ----------
__device__ __forceinline__ void fma4(float4& acc, float s, const float4& b) {
    acc.x += s * b.x; acc.y += s * b.y; acc.z += s * b.z; acc.w += s * b.w;
}

// ---------- kernel 1: ZS = z @ Wmsg[0:128], ZD = z @ Wmsg[128:256] (no bias) ----------
// grid (ceil(N/64), 2), block 256. BM=64 rows x 128 cols per block, 8x4 micro-tile/thread.
__global__ __launch_bounds__(256) void gemm_zszd(
    const float* __restrict__ z, const float* __restrict__ Wmsg,
    float* __restrict__ ZS, float* __restrict__ ZD, int N)
{
    __shared__ float At[64][132];  // +4 pad
    const int half = blockIdx.y;
    const float* B = Wmsg + (size_t)half * H * H;   // [k][c], row stride 128
    float* Out = half ? ZD : ZS;
    const int row0 = blockIdx.x * 64;
    const int t = threadIdx.x;

#pragma unroll
    for (int i = 0; i < 8; ++i) {
        int l = t + i * 256;
        int r = l >> 5, c4 = l & 31;
        int gr = row0 + r;
        float4 v = make_float4(0.f, 0.f, 0.f, 0.f);
        if (gr < N) v = ((const float4*)(z + (size_t)gr * H))[c4];
        *(float4*)&At[r][c4 * 4] = v;
    }
    __syncthreads();

    const int tx = t & 31;   // cols tx*4 .. tx*4+3
    const int ty = t >> 5;   // rows ty*8 .. ty*8+7
    float4 acc[8];
#pragma unroll
    for (int r = 0; r < 8; ++r) acc[r] = make_float4(0.f, 0.f, 0.f, 0.f);

    for (int k = 0; k < H; k += 4) {
        float4 b0 = ((const float4*)(B + (size_t)(k + 0) * H))[tx];
        float4 b1 = ((const float4*)(B + (size_t)(k + 1) * H))[tx];
        float4 b2 = ((const float4*)(B + (size_t)(k + 2) * H))[tx];
        float4 b3 = ((const float4*)(B + (size_t)(k + 3) * H))[tx];
#pragma unroll
        for (int r = 0; r < 8; ++r) {
            float4 a = *(const float4*)&At[ty * 8 + r][k];
            fma4(acc[r], a.x, b0);
            fma4(acc[r], a.y, b1);
            fma4(acc[r], a.z, b2);
            fma4(acc[r], a.w, b3);
        }
    }
#pragma unroll
    for (int r = 0; r < 8; ++r) {
        int gr = row0 + ty * 8 + r;
        if (gr < N) *(float4*)(Out + (size_t)gr * H + tx * 4) = acc[r];
    }
}

// ---------- CSR build: histogram -> 2-level exclusive scan -> scatter ----------
__global__ __launch_bounds__(256) void hist_dst(
    const int* __restrict__ dst, int* __restrict__ deg, int E)
{
    int e = blockIdx.x * blockDim.x + threadIdx.x;
    if (e < E) atomicAdd(&deg[dst[e]], 1);
}

// per-block inclusive scan of 256 deg entries; write exclusive, emit block sums
__global__ __launch_bounds__(256) void scan_a(
    const int* __restrict__ deg, int* __restrict__ startv, int* __restrict__ part, int N)
{
    __shared__ int sh[256];
    const int i = blockIdx.x * 256 + threadIdx.x;
    int v = (i < N) ? deg[i] : 0;
    sh[threadIdx.x] = v;
    __syncthreads();
#pragma unroll
    for (int off = 1; off < 256; off <<= 1) {
        int t = (threadIdx.x >= off) ? sh[threadIdx.x - off] : 0;
        __syncthreads();
        sh[threadIdx.x] += t;
        __syncthreads();
    }
    if (i < N) startv[i] = sh[threadIdx.x] - v;   // exclusive
    if (threadIdx.x == 255) part[blockIdx.x] = sh[255];
}

// single block: exclusive scan of <=256 block sums in place
__global__ __launch_bounds__(256) void scan_b(int* __restrict__ part, int nb)
{
    __shared__ int sh[256];
    int v = (threadIdx.x < nb) ? part[threadIdx.x] : 0;
    sh[threadIdx.x] = v;
    __syncthreads();
#pragma unroll
    for (int off = 1; off < 256; off <<= 1) {
        int t = (threadIdx.x >= off) ? sh[threadIdx.x - off] : 0;
        __syncthreads();
        sh[threadIdx.x] += t;
        __syncthreads();
    }
    if (threadIdx.x < nb) part[threadIdx.x] = sh[threadIdx.x] - v;
}

__global__ __launch_bounds__(256) void scan_c(
    int* __restrict__ startv, int* __restrict__ pos, const int* __restrict__ part, int N)
{
    int i = blockIdx.x * 256 + threadIdx.x;
    if (i < N) {
        int s = startv[i] + part[blockIdx.x];
        startv[i] = s;
        pos[i] = s;
    }
}

__global__ __launch_bounds__(256) void scatter_edges(
    const int* __restrict__ src, const int* __restrict__ dst,
    const float* __restrict__ wgt, int* __restrict__ pos,
    int2* __restrict__ ew, int E)
{
    int e = blockIdx.x * blockDim.x + threadIdx.x;
    if (e < E) {
        int p = atomicAdd(&pos[dst[e]], 1);
        ew[p] = make_int2(src[e], __float_as_int(wgt[e]));
    }
}

// ---------- aggregate: per node, max over its edges; finalize fused; agg written in-place over ZD ----------
// block 256 = 2 nodes x 128 cols
__global__ __launch_bounds__(256) void aggregate(
    const float* __restrict__ ZS, float* __restrict__ ZD,
    const float* __restrict__ bmsg, const float* __restrict__ wrow,
    const int* __restrict__ startv, const int* __restrict__ deg,
    const int2* __restrict__ ew, int N)
{
    const int node = blockIdx.x * 2 + (threadIdx.x >> 7);
    const int col = threadIdx.x & 127;
    if (node >= N) return;
    const int s = startv[node];
    const int d = deg[node];
    const float wr = wrow[col];
    float m = -__builtin_inff();
    int j = 0;
    for (; j + 1 < d; j += 2) {
        int2 e0 = ew[s + j];
        int2 e1 = ew[s + j + 1];
        float v0 = ZS[(size_t)e0.x * H + col] + __int_as_float(e0.y) * wr;
        float v1 = ZS[(size_t)e1.x * H + col] + __int_as_float(e1.y) * wr;
        m = fmaxf(m, fmaxf(v0, v1));
    }
    if (j < d) {
        int2 e0 = ew[s + j];
        m = fmaxf(m, ZS[(size_t)e0.x * H + col] + __int_as_float(e0.y) * wr);
    }
    const size_t o = (size_t)node * H + col;
    float r = (d > 0) ? (m + ZD[o] + bmsg[col]) : 0.f;
    ZD[o] = r;   // safe: this thread is the only reader/writer of ZD[o]
}

// ---------- kernel 4: out = [z | agg] @ Wupd + bupd ----------
__global__ __launch_bounds__(256) void gemm_upd(
    const float* __restrict__ z, const float* __restrict__ agg,
    const float* __restrict__ Wupd, const float* __restrict__ bupd,
    float* __restrict__ out, int N)
{
    __shared__ float At[32][260];
    const int row0 = blockIdx.x * 32;
    const int t = threadIdx.x;

#pragma unroll
    for (int i = 0; i < 8; ++i) {
        int l = t + i * 256;
        int r = l >> 6, c4 = l & 63;
        int gr = row0 + r;
        float4 v = make_float4(0.f, 0.f, 0.f, 0.f);
        if (gr < N) {
            if (c4 < 32) v = ((const float4*)(z + (size_t)gr * H))[c4];
            else         v = ((const float4*)(agg + (size_t)gr * H))[c4 - 32];
        }
        *(float4*)&At[r][c4 * 4] = v;
    }
    __syncthreads();

    const int tx = t & 31;
    const int ty = t >> 5;
    float4 acc[4];
#pragma unroll
    for (int r = 0; r < 4; ++r) acc[r] = make_float4(0.f, 0.f, 0.f, 0.f);

    for (int k = 0; k < 2 * H; k += 4) {
        float4 b0 = ((const float4*)(Wupd + (size_t)(k + 0) * H))[tx];
        float4 b1 = ((const float4*)(Wupd + (size_t)(k + 1) * H))[tx];
        float4 b2 = ((const float4*)(Wupd + (size_t)(k + 2) * H))[tx];
        float4 b3 = ((const float4*)(Wupd + (size_t)(k + 3) * H))[tx];
#pragma unroll
        for (int r = 0; r < 4; ++r) {
            float4 a = *(const float4*)&At[ty * 4 + r][k];
            fma4(acc[r], a.x, b0);
            fma4(acc[r], a.y, b1);
            fma4(acc[r], a.z, b2);
            fma4(acc[r], a.w, b3);
        }
    }
    float4 bias = ((const float4*)bupd)[tx];
#pragma unroll
    for (int r = 0; r < 4; ++r) {
        int gr = row0 + ty * 4 + r;
        if (gr < N) {
            acc[r].x += bias.x; acc[r].y += bias.y; acc[r].z += bias.z; acc[r].w += bias.w;
            *(float4*)(out + (size_t)gr * H + tx * 4) = acc[r];
        }
    }
}

extern "C" void kernel_launch(void* const* d_in, const int* in_sizes, int n_in,
                              void* d_out, int out_size, void* d_ws, size_t ws_size,
                              hipStream_t stream) {
    const float* z    = (const float*)d_in[0];   // [N,128]
    const int*   src  = (const int*)d_in[1];     // [E]
    const int*   dst  = (const int*)d_in[2];     // [E]
    const float* wgt  = (const float*)d_in[3];   // [E,1]
    const float* Wmsg = (const float*)d_in[4];   // [257,128]
    const float* bmsg = (const float*)d_in[5];   // [128]
    const float* Wupd = (const float*)d_in[6];   // [256,128]
    const float* bupd = (const float*)d_in[7];   // [128]
    float* out = (float*)d_out;

    const int N = in_sizes[0] / H;   // 50000
    const int E = in_sizes[1];       // 640000

    // ws layout
    float* ZS     = (float*)d_ws;                       // N*H
    float* ZD     = ZS + (size_t)N * H;                 // N*H (becomes agg in place)
    int*   deg    = (int*)(ZD + (size_t)N * H);         // N
    int*   startv = deg + N;                            // N
    int*   pos    = startv + N;                         // N
    int*   part   = pos + N;                            // 256
    int2*  ew     = (int2*)(part + 256);                // E

    const int nbN = (N + 255) / 256;
    const int nbE = (E + 255) / 256;

    hipMemsetAsync(deg, 0, (size_t)N * sizeof(int), stream);

    gemm_zszd<<<dim3((N + 63) / 64, 2), 256, 0, stream>>>(z, Wmsg, ZS, ZD, N);

    hist_dst<<<nbE, 256, 0, stream>>>(dst, deg, E);
    scan_a<<<nbN, 256, 0, stream>>>(deg, startv, part, N);
    scan_b<<<1, 256, 0, stream>>>(part, nbN);
    scan_c<<<nbN, 256, 0, stream>>>(startv, pos, part, N);
    scatter_edges<<<nbE, 256, 0, stream>>>(src, dst, wgt, pos, ew, E);

    aggregate<<<(N + 1) / 2, 256, 0, stream>>>(
        ZS, ZD, bmsg, Wmsg + (size_t)256 * H, startv, deg, ew, N);

    gemm_upd<<<(N + 31) / 32, 256, 0, stream>>>(z, ZD, Wupd, bupd, out, N);
}

// Round 3
// 190.570 us; speedup vs baseline: 3.1680x; 1.3387x over previous
//
#include <hip/hip_runtime.h>

#define H 128

typedef __attribute__((ext_vector_type(8))) short bf8;     // 8 x bf16 (4 VGPRs)
typedef __attribute__((ext_vector_type(4))) float f32x4;

__device__ __forceinline__ unsigned short f2bf(float f) {  // RNE f32 -> bf16
    unsigned u = __float_as_uint(f);
    return (unsigned short)((u + 0x7FFFu + ((u >> 16) & 1u)) >> 16);
}
__device__ __forceinline__ float bf2f(unsigned short b) {
    return __uint_as_float(((unsigned)b) << 16);
}

// ---------- prep: cast z -> bf16 into Aupd[:, :128]; build transposed bf16 weights ----------
__global__ __launch_bounds__(256) void prep(
    const float* __restrict__ z, const float* __restrict__ Wmsg, const float* __restrict__ Wupd,
    unsigned short* __restrict__ Az,    // Aupd [Npad][256] bf16
    unsigned short* __restrict__ WmT,   // [256 outcol][128 k]
    unsigned short* __restrict__ WuT,   // [128 outcol][256 k]
    int N)
{
    const int t = blockIdx.x * 256 + threadIdx.x;
    const int zi = t * 8;
    if (zi < N * H) {
        const int row = zi >> 7, c0 = zi & 127;
        const float4* p = (const float4*)(z + zi);
        float4 v0 = p[0], v1 = p[1];
        ushort4 o0, o1;
        o0.x = f2bf(v0.x); o0.y = f2bf(v0.y); o0.z = f2bf(v0.z); o0.w = f2bf(v0.w);
        o1.x = f2bf(v1.x); o1.y = f2bf(v1.y); o1.z = f2bf(v1.z); o1.w = f2bf(v1.w);
        ushort4* q = (ushort4*)(Az + (size_t)row * 256 + c0);
        q[0] = o0; q[1] = o1;
    }
    if (t < 256 * H) {  // WmT: t = c*128 + k ; c<128 -> Wmsg[k][c], c>=128 -> Wmsg[128+k][c-128]
        const int c = t >> 7, k = t & 127;
        WmT[t] = f2bf(Wmsg[(size_t)(k + (c & 128)) * H + (c & 127)]);
    }
    if (t < H * 256) {  // WuT: t = c*256 + k = Wupd[k][c]
        const int c = t >> 8, k = t & 255;
        WuT[t] = f2bf(Wupd[(size_t)k * H + c]);
    }
}

// ---------- GEMM1: ZSD[n][0:256] = z @ [Wmsg_s | Wmsg_d]  (bf16 in, bf16 out) ----------
// 4 waves; wave w owns out-cols [w*64, w*64+64). W frags in registers; grid-stride over 32-row tiles.
__global__ __launch_bounds__(256) void gemm_zszd_mfma(
    const unsigned short* __restrict__ Az,   // [Npad][256], cols 0..127 = z bf16
    const unsigned short* __restrict__ WmT,  // [256][128]
    unsigned short* __restrict__ ZSD,        // [Npad][256] bf16 out
    int N, int ntiles)
{
    const int l = threadIdx.x & 63;
    const int w = threadIdx.x >> 6;
    const int r = l & 15, g = l >> 4;
    const int colbase = w * 64;

    bf8 wf[4][4];  // [kk][nf]
#pragma unroll
    for (int nf = 0; nf < 4; ++nf)
#pragma unroll
        for (int kk = 0; kk < 4; ++kk)
            wf[kk][nf] = *(const bf8*)(WmT + (size_t)(colbase + nf * 16 + r) * H + kk * 32 + g * 8);

    const f32x4 zero = {0.f, 0.f, 0.f, 0.f};
    for (int tt = blockIdx.x; tt < ntiles; tt += gridDim.x) {
        const int row0 = tt * 32;
#pragma unroll
        for (int m = 0; m < 2; ++m) {
            bf8 zf[4];
#pragma unroll
            for (int kk = 0; kk < 4; ++kk)
                zf[kk] = *(const bf8*)(Az + (size_t)(row0 + m * 16 + r) * 256 + kk * 32 + g * 8);
            f32x4 acc[4] = {zero, zero, zero, zero};
#pragma unroll
            for (int kk = 0; kk < 4; ++kk)
#pragma unroll
                for (int nf = 0; nf < 4; ++nf)
                    acc[nf] = __builtin_amdgcn_mfma_f32_16x16x32_bf16(wf[kk][nf], zf[kk], acc[nf], 0, 0, 0);
            const int node = row0 + m * 16 + r;
            if (node < N) {
#pragma unroll
                for (int nf = 0; nf < 4; ++nf) {
                    ushort4 o;
                    o.x = f2bf(acc[nf][0]); o.y = f2bf(acc[nf][1]);
                    o.z = f2bf(acc[nf][2]); o.w = f2bf(acc[nf][3]);
                    *(ushort4*)(ZSD + (size_t)node * 256 + colbase + nf * 16 + g * 4) = o;
                }
            }
        }
    }
}

// ---------- CSR build ----------
__global__ __launch_bounds__(256) void hist_dst(
    const int* __restrict__ dst, int* __restrict__ deg, int E)
{
    int e = blockIdx.x * blockDim.x + threadIdx.x;
    if (e < E) atomicAdd(&deg[dst[e]], 1);
}

__global__ __launch_bounds__(256) void scan_a(
    const int* __restrict__ deg, int* __restrict__ startv, int* __restrict__ part, int N)
{
    __shared__ int sh[256];
    const int i = blockIdx.x * 256 + threadIdx.x;
    int v = (i < N) ? deg[i] : 0;
    sh[threadIdx.x] = v;
    __syncthreads();
#pragma unroll
    for (int off = 1; off < 256; off <<= 1) {
        int t = (threadIdx.x >= off) ? sh[threadIdx.x - off] : 0;
        __syncthreads();
        sh[threadIdx.x] += t;
        __syncthreads();
    }
    if (i < N) startv[i] = sh[threadIdx.x] - v;
    if (threadIdx.x == 255) part[blockIdx.x] = sh[255];
}

__global__ __launch_bounds__(256) void scan_b(int* __restrict__ part, int nb)
{
    __shared__ int sh[256];
    int v = (threadIdx.x < nb) ? part[threadIdx.x] : 0;
    sh[threadIdx.x] = v;
    __syncthreads();
#pragma unroll
    for (int off = 1; off < 256; off <<= 1) {
        int t = (threadIdx.x >= off) ? sh[threadIdx.x - off] : 0;
        __syncthreads();
        sh[threadIdx.x] += t;
        __syncthreads();
    }
    if (threadIdx.x < nb) part[threadIdx.x] = sh[threadIdx.x] - v;
}

__global__ __launch_bounds__(256) void scan_c(
    int* __restrict__ startv, int* __restrict__ pos, const int* __restrict__ part, int N)
{
    int i = blockIdx.x * 256 + threadIdx.x;
    if (i < N) {
        int s = startv[i] + part[blockIdx.x];
        startv[i] = s;
        pos[i] = s;
    }
}

__global__ __launch_bounds__(256) void scatter_edges(
    const int* __restrict__ src, const int* __restrict__ dst,
    const float* __restrict__ wgt, int* __restrict__ pos,
    int2* __restrict__ ew, int E)
{
    int e = blockIdx.x * blockDim.x + threadIdx.x;
    if (e < E) {
        int p = atomicAdd(&pos[dst[e]], 1);
        ew[p] = make_int2(src[e], __float_as_int(wgt[e]));
    }
}

// ---------- aggregate: agg[node][col] = max_e(ZS[src_e][col] + w_e*wrow[col]) + ZD + bmsg ----------
// writes bf16 directly into Aupd[:, 128:256]; 2 nodes x 128 cols per block
__global__ __launch_bounds__(256) void aggregate(
    const unsigned short* __restrict__ ZSD,  // [Npad][256] bf16
    unsigned short* __restrict__ Az,         // Aupd [Npad][256] bf16 (write cols 128..255)
    const float* __restrict__ bmsg, const float* __restrict__ wrow,
    const int* __restrict__ startv, const int* __restrict__ deg,
    const int2* __restrict__ ew, int N)
{
    const int node = blockIdx.x * 2 + (threadIdx.x >> 7);
    const int col = threadIdx.x & 127;
    if (node >= N) return;
    const int s = startv[node];
    const int d = deg[node];
    const float wr = wrow[col];
    float m = -__builtin_inff();
    int j = 0;
    for (; j + 1 < d; j += 2) {
        int2 e0 = ew[s + j];
        int2 e1 = ew[s + j + 1];
        float v0 = bf2f(ZSD[(size_t)e0.x * 256 + col]) + __int_as_float(e0.y) * wr;
        float v1 = bf2f(ZSD[(size_t)e1.x * 256 + col]) + __int_as_float(e1.y) * wr;
        m = fmaxf(m, fmaxf(v0, v1));
    }
    if (j < d) {
        int2 e0 = ew[s + j];
        m = fmaxf(m, bf2f(ZSD[(size_t)e0.x * 256 + col]) + __int_as_float(e0.y) * wr);
    }
    float res = (d > 0) ? (m + bf2f(ZSD[(size_t)node * 256 + 128 + col]) + bmsg[col]) : 0.f;
    Az[(size_t)node * 256 + 128 + col] = f2bf(res);
}

// ---------- GEMM2: out[n][0:128] = Aupd[n][0:256] @ Wupd + bupd (f32 out) ----------
__global__ __launch_bounds__(256) void gemm_upd_mfma(
    const unsigned short* __restrict__ Az,   // [Npad][256]
    const unsigned short* __restrict__ WuT,  // [128][256]
    const float* __restrict__ bupd,
    float* __restrict__ out, int N, int ntiles)
{
    const int l = threadIdx.x & 63;
    const int w = threadIdx.x >> 6;
    const int r = l & 15, g = l >> 4;
    const int colbase = w * 32;

    bf8 wf[8][2];  // [kk][nf]
#pragma unroll
    for (int nf = 0; nf < 2; ++nf)
#pragma unroll
        for (int kk = 0; kk < 8; ++kk)
            wf[kk][nf] = *(const bf8*)(WuT + (size_t)(colbase + nf * 16 + r) * 256 + kk * 32 + g * 8);
    float4 bias[2];
#pragma unroll
    for (int nf = 0; nf < 2; ++nf)
        bias[nf] = *(const float4*)(bupd + colbase + nf * 16 + g * 4);

    const f32x4 zero = {0.f, 0.f, 0.f, 0.f};
    for (int tt = blockIdx.x; tt < ntiles; tt += gridDim.x) {
        const int row0 = tt * 32;
#pragma unroll
        for (int m = 0; m < 2; ++m) {
            bf8 zf[8];
#pragma unroll
            for (int kk = 0; kk < 8; ++kk)
                zf[kk] = *(const bf8*)(Az + (size_t)(row0 + m * 16 + r) * 256 + kk * 32 + g * 8);
            f32x4 acc[2] = {zero, zero};
#pragma unroll
            for (int kk = 0; kk < 8; ++kk)
#pragma unroll
                for (int nf = 0; nf < 2; ++nf)
                    acc[nf] = __builtin_amdgcn_mfma_f32_16x16x32_bf16(wf[kk][nf], zf[kk], acc[nf], 0, 0, 0);
            const int node = row0 + m * 16 + r;
            if (node < N) {
#pragma unroll
                for (int nf = 0; nf < 2; ++nf) {
                    float4 o;
                    o.x = acc[nf][0] + bias[nf].x;
                    o.y = acc[nf][1] + bias[nf].y;
                    o.z = acc[nf][2] + bias[nf].z;
                    o.w = acc[nf][3] + bias[nf].w;
                    *(float4*)(out + (size_t)node * H + colbase + nf * 16 + g * 4) = o;
                }
            }
        }
    }
}

extern "C" void kernel_launch(void* const* d_in, const int* in_sizes, int n_in,
                              void* d_out, int out_size, void* d_ws, size_t ws_size,
                              hipStream_t stream) {
    const float* z    = (const float*)d_in[0];
    const int*   src  = (const int*)d_in[1];
    const int*   dst  = (const int*)d_in[2];
    const float* wgt  = (const float*)d_in[3];
    const float* Wmsg = (const float*)d_in[4];   // [257][128]
    const float* bmsg = (const float*)d_in[5];
    const float* Wupd = (const float*)d_in[6];   // [256][128]
    const float* bupd = (const float*)d_in[7];
    float* out = (float*)d_out;

    const int N = in_sizes[0] / H;            // 50000
    const int E = in_sizes[1];                // 640000
    const int Npad = ((N + 31) / 32) * 32;    // 50016
    const int ntiles = Npad / 32;             // 1563

    // ws layout (16B aligned chunks)
    unsigned short* Az  = (unsigned short*)d_ws;            // [Npad][256] bf16 ([z | agg])
    unsigned short* ZSD = Az + (size_t)Npad * 256;          // [Npad][256] bf16 ([ZS | ZD])
    unsigned short* WmT = ZSD + (size_t)Npad * 256;         // 256*128
    unsigned short* WuT = WmT + 256 * H;                    // 128*256
    int*  deg    = (int*)(WuT + H * 256);                   // N
    int*  startv = deg + N;                                 // N
    int*  pos    = startv + N;                              // N
    int*  part   = pos + N;                                 // 256
    int2* ew     = (int2*)(part + 256);                     // E

    const int nbN = (N + 255) / 256;
    const int nbE = (E + 255) / 256;

    hipMemsetAsync(deg, 0, (size_t)N * sizeof(int), stream);

    prep<<<(N * H / 8 + 255) / 256, 256, 0, stream>>>(z, Wmsg, Wupd, Az, WmT, WuT, N);

    gemm_zszd_mfma<<<784, 256, 0, stream>>>(Az, WmT, ZSD, N, ntiles);

    hist_dst<<<nbE, 256, 0, stream>>>(dst, deg, E);
    scan_a<<<nbN, 256, 0, stream>>>(deg, startv, part, N);
    scan_b<<<1, 256, 0, stream>>>(part, nbN);
    scan_c<<<nbN, 256, 0, stream>>>(startv, pos, part, N);
    scatter_edges<<<nbE, 256, 0, stream>>>(src, dst, wgt, pos, ew, E);

    aggregate<<<(N + 1) / 2, 256, 0, stream>>>(
        ZSD, Az, bmsg, Wmsg + (size_t)256 * H, startv, deg, ew, N);

    gemm_upd_mfma<<<784, 256, 0, stream>>>(Az, WuT, bupd, out, N, ntiles);
}

// Round 4
// 173.315 us; speedup vs baseline: 3.4834x; 1.0996x over previous
//
#include <hip/hip_runtime.h>

#define H 128

typedef __attribute__((ext_vector_type(8))) short bf8;     // 8 x bf16 (4 VGPRs)
typedef __attribute__((ext_vector_type(8))) unsigned short u16x8;
typedef __attribute__((ext_vector_type(4))) float f32x4;

__device__ __forceinline__ unsigned short f2bf(float f) {  // RNE f32 -> bf16
    unsigned u = __float_as_uint(f);
    return (unsigned short)((u + 0x7FFFu + ((u >> 16) & 1u)) >> 16);
}
__device__ __forceinline__ float bf2f(unsigned short b) {
    return __uint_as_float(((unsigned)b) << 16);
}

// ---------- prep: cast z -> bf16 into Aupd[:, :128]; build transposed bf16 weights ----------
__global__ __launch_bounds__(256) void prep(
    const float* __restrict__ z, const float* __restrict__ Wmsg, const float* __restrict__ Wupd,
    unsigned short* __restrict__ Az,    // Aupd [Npad][256] bf16
    unsigned short* __restrict__ WmT,   // [256 outcol][128 k]
    unsigned short* __restrict__ WuT,   // [128 outcol][256 k]
    int N)
{
    const int t = blockIdx.x * 256 + threadIdx.x;
    const int zi = t * 8;
    if (zi < N * H) {
        const int row = zi >> 7, c0 = zi & 127;
        const float4* p = (const float4*)(z + zi);
        float4 v0 = p[0], v1 = p[1];
        ushort4 o0, o1;
        o0.x = f2bf(v0.x); o0.y = f2bf(v0.y); o0.z = f2bf(v0.z); o0.w = f2bf(v0.w);
        o1.x = f2bf(v1.x); o1.y = f2bf(v1.y); o1.z = f2bf(v1.z); o1.w = f2bf(v1.w);
        ushort4* q = (ushort4*)(Az + (size_t)row * 256 + c0);
        q[0] = o0; q[1] = o1;
    }
    if (t < 256 * H) {  // WmT: t = c*128 + k ; c<128 -> Wmsg[k][c], c>=128 -> Wmsg[128+k][c-128]
        const int c = t >> 7, k = t & 127;
        WmT[t] = f2bf(Wmsg[(size_t)(k + (c & 128)) * H + (c & 127)]);
    }
    if (t < H * 256) {  // WuT: t = c*256 + k = Wupd[k][c]
        const int c = t >> 8, k = t & 255;
        WuT[t] = f2bf(Wupd[(size_t)k * H + c]);
    }
}

// ---------- GEMM1: ZSD[n][0:256] = z @ [Wmsg_s | Wmsg_d]  (bf16 in, bf16 out) ----------
__global__ __launch_bounds__(256) void gemm_zszd_mfma(
    const unsigned short* __restrict__ Az,   // [Npad][256], cols 0..127 = z bf16
    const unsigned short* __restrict__ WmT,  // [256][128]
    unsigned short* __restrict__ ZSD,        // [Npad][256] bf16 out
    int N, int ntiles)
{
    const int l = threadIdx.x & 63;
    const int w = threadIdx.x >> 6;
    const int r = l & 15, g = l >> 4;
    const int colbase = w * 64;

    bf8 wf[4][4];  // [kk][nf]
#pragma unroll
    for (int nf = 0; nf < 4; ++nf)
#pragma unroll
        for (int kk = 0; kk < 4; ++kk)
            wf[kk][nf] = *(const bf8*)(WmT + (size_t)(colbase + nf * 16 + r) * H + kk * 32 + g * 8);

    const f32x4 zero = {0.f, 0.f, 0.f, 0.f};
    for (int tt = blockIdx.x; tt < ntiles; tt += gridDim.x) {
        const int row0 = tt * 32;
#pragma unroll
        for (int m = 0; m < 2; ++m) {
            bf8 zf[4];
#pragma unroll
            for (int kk = 0; kk < 4; ++kk)
                zf[kk] = *(const bf8*)(Az + (size_t)(row0 + m * 16 + r) * 256 + kk * 32 + g * 8);
            f32x4 acc[4] = {zero, zero, zero, zero};
#pragma unroll
            for (int kk = 0; kk < 4; ++kk)
#pragma unroll
                for (int nf = 0; nf < 4; ++nf)
                    acc[nf] = __builtin_amdgcn_mfma_f32_16x16x32_bf16(wf[kk][nf], zf[kk], acc[nf], 0, 0, 0);
            const int node = row0 + m * 16 + r;
            if (node < N) {
#pragma unroll
                for (int nf = 0; nf < 4; ++nf) {
                    ushort4 o;
                    o.x = f2bf(acc[nf][0]); o.y = f2bf(acc[nf][1]);
                    o.z = f2bf(acc[nf][2]); o.w = f2bf(acc[nf][3]);
                    *(ushort4*)(ZSD + (size_t)node * 256 + colbase + nf * 16 + g * 4) = o;
                }
            }
        }
    }
}

// ---------- CSR build ----------
__global__ __launch_bounds__(256) void hist_dst(
    const int* __restrict__ dst, int* __restrict__ deg, int E)
{
    int e = blockIdx.x * blockDim.x + threadIdx.x;
    if (e < E) atomicAdd(&deg[dst[e]], 1);
}

__global__ __launch_bounds__(256) void scan_a(
    const int* __restrict__ deg, int* __restrict__ startv, int* __restrict__ part, int N)
{
    __shared__ int sh[256];
    const int i = blockIdx.x * 256 + threadIdx.x;
    int v = (i < N) ? deg[i] : 0;
    sh[threadIdx.x] = v;
    __syncthreads();
#pragma unroll
    for (int off = 1; off < 256; off <<= 1) {
        int t = (threadIdx.x >= off) ? sh[threadIdx.x - off] : 0;
        __syncthreads();
        sh[threadIdx.x] += t;
        __syncthreads();
    }
    if (i < N) startv[i] = sh[threadIdx.x] - v;
    if (threadIdx.x == 255) part[blockIdx.x] = sh[255];
}

__global__ __launch_bounds__(256) void scan_b(int* __restrict__ part, int nb)
{
    __shared__ int sh[256];
    int v = (threadIdx.x < nb) ? part[threadIdx.x] : 0;
    sh[threadIdx.x] = v;
    __syncthreads();
#pragma unroll
    for (int off = 1; off < 256; off <<= 1) {
        int t = (threadIdx.x >= off) ? sh[threadIdx.x - off] : 0;
        __syncthreads();
        sh[threadIdx.x] += t;
        __syncthreads();
    }
    if (threadIdx.x < nb) part[threadIdx.x] = sh[threadIdx.x] - v;
}

__global__ __launch_bounds__(256) void scan_c(
    int* __restrict__ startv, int* __restrict__ pos, const int* __restrict__ part, int N)
{
    int i = blockIdx.x * 256 + threadIdx.x;
    if (i < N) {
        int s = startv[i] + part[blockIdx.x];
        startv[i] = s;
        pos[i] = s;
    }
}

__global__ __launch_bounds__(256) void scatter_edges(
    const int* __restrict__ src, const int* __restrict__ dst,
    const float* __restrict__ wgt, int* __restrict__ pos,
    int2* __restrict__ ew, int E)
{
    int e = blockIdx.x * blockDim.x + threadIdx.x;
    if (e < E) {
        int p = atomicAdd(&pos[dst[e]], 1);
        ew[p] = make_int2(src[e], __float_as_int(wgt[e]));
    }
}

// ---------- aggregate (wave-per-node): agg = max_e(ZS[src_e] + w_e*wrow) + ZD + bmsg ----------
// 4 waves/block = 4 nodes. Lane = (sub 0..3 edge slot) x (c16 0..15 col group of 8).
__global__ __launch_bounds__(256) void aggregate(
    const unsigned short* __restrict__ ZSD,  // [Npad][256] bf16
    unsigned short* __restrict__ Az,         // Aupd, write cols 128..255
    const float* __restrict__ bmsg, const float* __restrict__ wrow,
    const int* __restrict__ startv, const int* __restrict__ deg,
    const int2* __restrict__ ew, int N)
{
    const int node = blockIdx.x * 4 + (threadIdx.x >> 6);
    if (node >= N) return;
    const int l = threadIdx.x & 63;
    const int sub = l >> 4;        // edge slot
    const int c16 = l & 15;        // cols c16*8 .. +7

    const int s = startv[node];
    const int d = deg[node];

    float wr[8];
    {
        float4 w0 = *(const float4*)(wrow + c16 * 8);
        float4 w1 = *(const float4*)(wrow + c16 * 8 + 4);
        wr[0] = w0.x; wr[1] = w0.y; wr[2] = w0.z; wr[3] = w0.w;
        wr[4] = w1.x; wr[5] = w1.y; wr[6] = w1.z; wr[7] = w1.w;
    }

    const float NINF = -__builtin_inff();
    float m[8];
#pragma unroll
    for (int i = 0; i < 8; ++i) m[i] = NINF;

    const int iters = (d + 3) >> 2;
    for (int j = 0; j < iters; ++j) {
        const int slot = j * 4 + sub;
        const bool ok = slot < d;
        int2 e = ew[s + (ok ? slot : 0)];
        u16x8 v = *(const u16x8*)(ZSD + (size_t)e.x * 256 + c16 * 8);
        const float w = __int_as_float(e.y);
#pragma unroll
        for (int i = 0; i < 8; ++i) {
            float t = bf2f((unsigned short)v[i]) + w * wr[i];
            m[i] = fmaxf(m[i], ok ? t : NINF);
        }
    }
    // merge the 4 edge slots: lanes l, l^16, l^32, l^48
#pragma unroll
    for (int i = 0; i < 8; ++i) {
        m[i] = fmaxf(m[i], __shfl_xor(m[i], 16));
        m[i] = fmaxf(m[i], __shfl_xor(m[i], 32));
    }

    if (sub == 0) {
        u16x8 zd = *(const u16x8*)(ZSD + (size_t)node * 256 + 128 + c16 * 8);
        float bm[8];
        float4 b0 = *(const float4*)(bmsg + c16 * 8);
        float4 b1 = *(const float4*)(bmsg + c16 * 8 + 4);
        bm[0] = b0.x; bm[1] = b0.y; bm[2] = b0.z; bm[3] = b0.w;
        bm[4] = b1.x; bm[5] = b1.y; bm[6] = b1.z; bm[7] = b1.w;
        u16x8 o;
#pragma unroll
        for (int i = 0; i < 8; ++i) {
            float r = (d > 0) ? (m[i] + bf2f((unsigned short)zd[i]) + bm[i]) : 0.f;
            o[i] = f2bf(r);
        }
        *(u16x8*)(Az + (size_t)node * 256 + 128 + c16 * 8) = o;
    }
}

// ---------- GEMM2: out[n][0:128] = Aupd[n][0:256] @ Wupd + bupd (f32 out) ----------
__global__ __launch_bounds__(256) void gemm_upd_mfma(
    const unsigned short* __restrict__ Az,   // [Npad][256]
    const unsigned short* __restrict__ WuT,  // [128][256]
    const float* __restrict__ bupd,
    float* __restrict__ out, int N, int ntiles)
{
    const int l = threadIdx.x & 63;
    const int w = threadIdx.x >> 6;
    const int r = l & 15, g = l >> 4;
    const int colbase = w * 32;

    bf8 wf[8][2];
#pragma unroll
    for (int nf = 0; nf < 2; ++nf)
#pragma unroll
        for (int kk = 0; kk < 8; ++kk)
            wf[kk][nf] = *(const bf8*)(WuT + (size_t)(colbase + nf * 16 + r) * 256 + kk * 32 + g * 8);
    float4 bias[2];
#pragma unroll
    for (int nf = 0; nf < 2; ++nf)
        bias[nf] = *(const float4*)(bupd + colbase + nf * 16 + g * 4);

    const f32x4 zero = {0.f, 0.f, 0.f, 0.f};
    for (int tt = blockIdx.x; tt < ntiles; tt += gridDim.x) {
        const int row0 = tt * 32;
#pragma unroll
        for (int m = 0; m < 2; ++m) {
            bf8 zf[8];
#pragma unroll
            for (int kk = 0; kk < 8; ++kk)
                zf[kk] = *(const bf8*)(Az + (size_t)(row0 + m * 16 + r) * 256 + kk * 32 + g * 8);
            f32x4 acc[2] = {zero, zero};
#pragma unroll
            for (int kk = 0; kk < 8; ++kk)
#pragma unroll
                for (int nf = 0; nf < 2; ++nf)
                    acc[nf] = __builtin_amdgcn_mfma_f32_16x16x32_bf16(wf[kk][nf], zf[kk], acc[nf], 0, 0, 0);
            const int node = row0 + m * 16 + r;
            if (node < N) {
#pragma unroll
                for (int nf = 0; nf < 2; ++nf) {
                    float4 o;
                    o.x = acc[nf][0] + bias[nf].x;
                    o.y = acc[nf][1] + bias[nf].y;
                    o.z = acc[nf][2] + bias[nf].z;
                    o.w = acc[nf][3] + bias[nf].w;
                    *(float4*)(out + (size_t)node * H + colbase + nf * 16 + g * 4) = o;
                }
            }
        }
    }
}

extern "C" void kernel_launch(void* const* d_in, const int* in_sizes, int n_in,
                              void* d_out, int out_size, void* d_ws, size_t ws_size,
                              hipStream_t stream) {
    const float* z    = (const float*)d_in[0];
    const int*   src  = (const int*)d_in[1];
    const int*   dst  = (const int*)d_in[2];
    const float* wgt  = (const float*)d_in[3];
    const float* Wmsg = (const float*)d_in[4];   // [257][128]
    const float* bmsg = (const float*)d_in[5];
    const float* Wupd = (const float*)d_in[6];   // [256][128]
    const float* bupd = (const float*)d_in[7];
    float* out = (float*)d_out;

    const int N = in_sizes[0] / H;            // 50000
    const int E = in_sizes[1];                // 640000
    const int Npad = ((N + 31) / 32) * 32;    // 50016
    const int ntiles = Npad / 32;             // 1563

    unsigned short* Az  = (unsigned short*)d_ws;            // [Npad][256] bf16 ([z | agg])
    unsigned short* ZSD = Az + (size_t)Npad * 256;          // [Npad][256] bf16 ([ZS | ZD])
    unsigned short* WmT = ZSD + (size_t)Npad * 256;         // 256*128
    unsigned short* WuT = WmT + 256 * H;                    // 128*256
    int*  deg    = (int*)(WuT + H * 256);                   // N
    int*  startv = deg + N;                                 // N
    int*  pos    = startv + N;                              // N
    int*  part   = pos + N;                                 // 256
    int2* ew     = (int2*)(part + 256);                     // E

    const int nbN = (N + 255) / 256;
    const int nbE = (E + 255) / 256;

    hipMemsetAsync(deg, 0, (size_t)N * sizeof(int), stream);

    prep<<<(N * H / 8 + 255) / 256, 256, 0, stream>>>(z, Wmsg, Wupd, Az, WmT, WuT, N);

    gemm_zszd_mfma<<<784, 256, 0, stream>>>(Az, WmT, ZSD, N, ntiles);

    hist_dst<<<nbE, 256, 0, stream>>>(dst, deg, E);
    scan_a<<<nbN, 256, 0, stream>>>(deg, startv, part, N);
    scan_b<<<1, 256, 0, stream>>>(part, nbN);
    scan_c<<<nbN, 256, 0, stream>>>(startv, pos, part, N);
    scatter_edges<<<nbE, 256, 0, stream>>>(src, dst, wgt, pos, ew, E);

    aggregate<<<(N + 3) / 4, 256, 0, stream>>>(
        ZSD, Az, bmsg, Wmsg + (size_t)256 * H, startv, deg, ew, N);

    gemm_upd_mfma<<<784, 256, 0, stream>>>(Az, WuT, bupd, out, N, ntiles);
}

// Round 5
// 160.774 us; speedup vs baseline: 3.7551x; 1.0780x over previous
//
#include <hip/hip_runtime.h>

#define H 128

typedef __attribute__((ext_vector_type(8))) short bf8;     // 8 x bf16 (4 VGPRs)
typedef __attribute__((ext_vector_type(8))) unsigned short u16x8;
typedef __attribute__((ext_vector_type(4))) float f32x4;

__device__ __forceinline__ unsigned short f2bf(float f) {  // RNE f32 -> bf16
    unsigned u = __float_as_uint(f);
    return (unsigned short)((u + 0x7FFFu + ((u >> 16) & 1u)) >> 16);
}
__device__ __forceinline__ float bf2f(unsigned short b) {
    return __uint_as_float(((unsigned)b) << 16);
}

// ---------- prep: cast z->bf16 into Az[:, :128]; transposed bf16 weights; zero deg; -inf sentinel row ----------
__global__ __launch_bounds__(256) void prep(
    const float* __restrict__ z, const float* __restrict__ Wmsg, const float* __restrict__ Wupd,
    unsigned short* __restrict__ Az,    // Aupd [Npad][256] bf16
    unsigned short* __restrict__ WmT,   // [256 outcol][128 k]
    unsigned short* __restrict__ WuT,   // [128 outcol][256 k]
    int* __restrict__ deg,
    unsigned short* __restrict__ ZSD,   // sentinel row N: cols 0..127 = bf16 -inf
    int N)
{
    const int t = blockIdx.x * 256 + threadIdx.x;
    const int zi = t * 8;
    if (zi < N * H) {
        const int row = zi >> 7, c0 = zi & 127;
        const float4* p = (const float4*)(z + zi);
        float4 v0 = p[0], v1 = p[1];
        ushort4 o0, o1;
        o0.x = f2bf(v0.x); o0.y = f2bf(v0.y); o0.z = f2bf(v0.z); o0.w = f2bf(v0.w);
        o1.x = f2bf(v1.x); o1.y = f2bf(v1.y); o1.z = f2bf(v1.z); o1.w = f2bf(v1.w);
        ushort4* q = (ushort4*)(Az + (size_t)row * 256 + c0);
        q[0] = o0; q[1] = o1;
    }
    if (t < N) deg[t] = 0;
    if (t < 16) {  // sentinel: ZSD[N][0..127] = -inf bf16
        u16x8 s;
#pragma unroll
        for (int i = 0; i < 8; ++i) s[i] = 0xFF80;
        *(u16x8*)(ZSD + (size_t)N * 256 + t * 8) = s;
    }
    if (t < 256 * H) {  // WmT: t = c*128 + k ; c<128 -> Wmsg[k][c], c>=128 -> Wmsg[128+k][c-128]
        const int c = t >> 7, k = t & 127;
        WmT[t] = f2bf(Wmsg[(size_t)(k + (c & 128)) * H + (c & 127)]);
    }
    if (t < H * 256) {  // WuT: t = c*256 + k = Wupd[k][c]
        const int c = t >> 8, k = t & 255;
        WuT[t] = f2bf(Wupd[(size_t)k * H + c]);
    }
}

// ---------- GEMM1: ZSD[n][0:256] = z @ [Wmsg_s | Wmsg_d]  (bf16 in, bf16 out) ----------
__global__ __launch_bounds__(256) void gemm_zszd_mfma(
    const unsigned short* __restrict__ Az,   // [Npad][256], cols 0..127 = z bf16
    const unsigned short* __restrict__ WmT,  // [256][128]
    unsigned short* __restrict__ ZSD,        // [Npad][256] bf16 out
    int N, int ntiles)
{
    const int l = threadIdx.x & 63;
    const int w = threadIdx.x >> 6;
    const int r = l & 15, g = l >> 4;
    const int colbase = w * 64;

    bf8 wf[4][4];  // [kk][nf]
#pragma unroll
    for (int nf = 0; nf < 4; ++nf)
#pragma unroll
        for (int kk = 0; kk < 4; ++kk)
            wf[kk][nf] = *(const bf8*)(WmT + (size_t)(colbase + nf * 16 + r) * H + kk * 32 + g * 8);

    const f32x4 zero = {0.f, 0.f, 0.f, 0.f};
    for (int tt = blockIdx.x; tt < ntiles; tt += gridDim.x) {
        const int row0 = tt * 32;
#pragma unroll
        for (int m = 0; m < 2; ++m) {
            bf8 zf[4];
#pragma unroll
            for (int kk = 0; kk < 4; ++kk)
                zf[kk] = *(const bf8*)(Az + (size_t)(row0 + m * 16 + r) * 256 + kk * 32 + g * 8);
            f32x4 acc[4] = {zero, zero, zero, zero};
#pragma unroll
            for (int kk = 0; kk < 4; ++kk)
#pragma unroll
                for (int nf = 0; nf < 4; ++nf)
                    acc[nf] = __builtin_amdgcn_mfma_f32_16x16x32_bf16(wf[kk][nf], zf[kk], acc[nf], 0, 0, 0);
            const int node = row0 + m * 16 + r;
            if (node < N) {
#pragma unroll
                for (int nf = 0; nf < 4; ++nf) {
                    ushort4 o;
                    o.x = f2bf(acc[nf][0]); o.y = f2bf(acc[nf][1]);
                    o.z = f2bf(acc[nf][2]); o.w = f2bf(acc[nf][3]);
                    *(ushort4*)(ZSD + (size_t)node * 256 + colbase + nf * 16 + g * 4) = o;
                }
            }
        }
    }
}

// ---------- CSR build (padded to multiples of 4 edges per node) ----------
__global__ __launch_bounds__(256) void hist_dst(
    const int* __restrict__ dst, int* __restrict__ deg, int E)
{
    int e = blockIdx.x * blockDim.x + threadIdx.x;
    if (e < E) atomicAdd(&deg[dst[e]], 1);
}

// scan over PADDED degrees
__global__ __launch_bounds__(256) void scan_a(
    const int* __restrict__ deg, int* __restrict__ startv, int* __restrict__ part, int N)
{
    __shared__ int sh[256];
    const int i = blockIdx.x * 256 + threadIdx.x;
    int v = (i < N) ? ((deg[i] + 3) & ~3) : 0;
    sh[threadIdx.x] = v;
    __syncthreads();
#pragma unroll
    for (int off = 1; off < 256; off <<= 1) {
        int t = (threadIdx.x >= off) ? sh[threadIdx.x - off] : 0;
        __syncthreads();
        sh[threadIdx.x] += t;
        __syncthreads();
    }
    if (i < N) startv[i] = sh[threadIdx.x] - v;
    if (threadIdx.x == 255) part[blockIdx.x] = sh[255];
}

__global__ __launch_bounds__(256) void scan_b(int* __restrict__ part, int nb)
{
    __shared__ int sh[256];
    int v = (threadIdx.x < nb) ? part[threadIdx.x] : 0;
    sh[threadIdx.x] = v;
    __syncthreads();
#pragma unroll
    for (int off = 1; off < 256; off <<= 1) {
        int t = (threadIdx.x >= off) ? sh[threadIdx.x - off] : 0;
        __syncthreads();
        sh[threadIdx.x] += t;
        __syncthreads();
    }
    if (threadIdx.x < nb) part[threadIdx.x] = sh[threadIdx.x] - v;
}

// finalize startv, init pos, and fill the pad slots with sentinel edges (src=N, w=0)
__global__ __launch_bounds__(256) void scan_c(
    int* __restrict__ startv, int* __restrict__ pos, const int* __restrict__ part,
    const int* __restrict__ deg, int2* __restrict__ ew, int N)
{
    int i = blockIdx.x * 256 + threadIdx.x;
    if (i < N) {
        int s = startv[i] + part[blockIdx.x];
        startv[i] = s;
        pos[i] = s;
        const int d = deg[i];
        const int dpad = (d + 3) & ~3;
        for (int j = d; j < dpad; ++j) ew[s + j] = make_int2(N, 0);
    }
}

__global__ __launch_bounds__(256) void scatter_edges(
    const int* __restrict__ src, const int* __restrict__ dst,
    const float* __restrict__ wgt, int* __restrict__ pos,
    int2* __restrict__ ew, int E)
{
    int e = blockIdx.x * blockDim.x + threadIdx.x;
    if (e < E) {
        int p = atomicAdd(&pos[dst[e]], 1);
        ew[p] = make_int2(src[e], __float_as_int(wgt[e]));
    }
}

// ---------- aggregate (wave-per-node, padded CSR, no tail select) ----------
// 4 waves/block = 4 nodes. Lane = (sub 0..3 edge slot) x (c16 0..15 col group of 8).
__global__ __launch_bounds__(256) void aggregate(
    const unsigned short* __restrict__ ZSD,  // [Npad][256] bf16 (+ sentinel row N)
    unsigned short* __restrict__ Az,         // Aupd, write cols 128..255
    const float* __restrict__ bmsg, const float* __restrict__ wrow,
    const int* __restrict__ startv, const int* __restrict__ deg,
    const int2* __restrict__ ew, int N)
{
    const int node = blockIdx.x * 4 + (threadIdx.x >> 6);
    if (node >= N) return;
    const int l = threadIdx.x & 63;
    const int sub = l >> 4;        // edge slot
    const int c16 = l & 15;        // cols c16*8 .. +7

    const int s = startv[node];
    const int d = deg[node];
    const int iters = (d + 3) >> 2;

    float wr[8];
    {
        float4 w0 = *(const float4*)(wrow + c16 * 8);
        float4 w1 = *(const float4*)(wrow + c16 * 8 + 4);
        wr[0] = w0.x; wr[1] = w0.y; wr[2] = w0.z; wr[3] = w0.w;
        wr[4] = w1.x; wr[5] = w1.y; wr[6] = w1.z; wr[7] = w1.w;
    }

    const float NINF = -__builtin_inff();
    float m[8];
#pragma unroll
    for (int i = 0; i < 8; ++i) m[i] = NINF;

    const int2* ep = ew + s + sub;
#pragma unroll 2
    for (int j = 0; j < iters; ++j) {
        int2 e = ep[j * 4];
        u16x8 v = *(const u16x8*)(ZSD + (size_t)e.x * 256 + c16 * 8);
        const float w = __int_as_float(e.y);
#pragma unroll
        for (int i = 0; i < 8; ++i)
            m[i] = fmaxf(m[i], __builtin_fmaf(w, wr[i], bf2f((unsigned short)v[i])));
    }
    // merge the 4 edge slots: lanes l, l^16, l^32, l^48
#pragma unroll
    for (int i = 0; i < 8; ++i) {
        m[i] = fmaxf(m[i], __shfl_xor(m[i], 16));
        m[i] = fmaxf(m[i], __shfl_xor(m[i], 32));
    }

    if (sub == 0) {
        u16x8 zd = *(const u16x8*)(ZSD + (size_t)node * 256 + 128 + c16 * 8);
        float bm[8];
        float4 b0 = *(const float4*)(bmsg + c16 * 8);
        float4 b1 = *(const float4*)(bmsg + c16 * 8 + 4);
        bm[0] = b0.x; bm[1] = b0.y; bm[2] = b0.z; bm[3] = b0.w;
        bm[4] = b1.x; bm[5] = b1.y; bm[6] = b1.z; bm[7] = b1.w;
        u16x8 o;
#pragma unroll
        for (int i = 0; i < 8; ++i) {
            float r = (d > 0) ? (m[i] + bf2f((unsigned short)zd[i]) + bm[i]) : 0.f;
            o[i] = f2bf(r);
        }
        *(u16x8*)(Az + (size_t)node * 256 + 128 + c16 * 8) = o;
    }
}

// ---------- GEMM2: out[n][0:128] = Aupd[n][0:256] @ Wupd + bupd (f32 out) ----------
__global__ __launch_bounds__(256) void gemm_upd_mfma(
    const unsigned short* __restrict__ Az,   // [Npad][256]
    const unsigned short* __restrict__ WuT,  // [128][256]
    const float* __restrict__ bupd,
    float* __restrict__ out, int N, int ntiles)
{
    const int l = threadIdx.x & 63;
    const int w = threadIdx.x >> 6;
    const int r = l & 15, g = l >> 4;
    const int colbase = w * 32;

    bf8 wf[8][2];
#pragma unroll
    for (int nf = 0; nf < 2; ++nf)
#pragma unroll
        for (int kk = 0; kk < 8; ++kk)
            wf[kk][nf] = *(const bf8*)(WuT + (size_t)(colbase + nf * 16 + r) * 256 + kk * 32 + g * 8);
    float4 bias[2];
#pragma unroll
    for (int nf = 0; nf < 2; ++nf)
        bias[nf] = *(const float4*)(bupd + colbase + nf * 16 + g * 4);

    const f32x4 zero = {0.f, 0.f, 0.f, 0.f};
    for (int tt = blockIdx.x; tt < ntiles; tt += gridDim.x) {
        const int row0 = tt * 32;
#pragma unroll
        for (int m = 0; m < 2; ++m) {
            bf8 zf[8];
#pragma unroll
            for (int kk = 0; kk < 8; ++kk)
                zf[kk] = *(const bf8*)(Az + (size_t)(row0 + m * 16 + r) * 256 + kk * 32 + g * 8);
            f32x4 acc[2] = {zero, zero};
#pragma unroll
            for (int kk = 0; kk < 8; ++kk)
#pragma unroll
                for (int nf = 0; nf < 2; ++nf)
                    acc[nf] = __builtin_amdgcn_mfma_f32_16x16x32_bf16(wf[kk][nf], zf[kk], acc[nf], 0, 0, 0);
            const int node = row0 + m * 16 + r;
            if (node < N) {
#pragma unroll
                for (int nf = 0; nf < 2; ++nf) {
                    float4 o;
                    o.x = acc[nf][0] + bias[nf].x;
                    o.y = acc[nf][1] + bias[nf].y;
                    o.z = acc[nf][2] + bias[nf].z;
                    o.w = acc[nf][3] + bias[nf].w;
                    *(float4*)(out + (size_t)node * H + colbase + nf * 16 + g * 4) = o;
                }
            }
        }
    }
}

extern "C" void kernel_launch(void* const* d_in, const int* in_sizes, int n_in,
                              void* d_out, int out_size, void* d_ws, size_t ws_size,
                              hipStream_t stream) {
    const float* z    = (const float*)d_in[0];
    const int*   src  = (const int*)d_in[1];
    const int*   dst  = (const int*)d_in[2];
    const float* wgt  = (const float*)d_in[3];
    const float* Wmsg = (const float*)d_in[4];   // [257][128]
    const float* bmsg = (const float*)d_in[5];
    const float* Wupd = (const float*)d_in[6];   // [256][128]
    const float* bupd = (const float*)d_in[7];
    float* out = (float*)d_out;

    const int N = in_sizes[0] / H;            // 50000
    const int E = in_sizes[1];                // 640000
    const int Npad = ((N + 31) / 32) * 32;    // 50016
    const int ntiles = Npad / 32;             // 1563

    unsigned short* Az  = (unsigned short*)d_ws;            // [Npad][256] bf16 ([z | agg])
    unsigned short* ZSD = Az + (size_t)Npad * 256;          // [Npad][256] bf16 ([ZS | ZD] + sentinel row N)
    unsigned short* WmT = ZSD + (size_t)Npad * 256;         // 256*128
    unsigned short* WuT = WmT + 256 * H;                    // 128*256
    int*  deg    = (int*)(WuT + H * 256);                   // N
    int*  startv = deg + N;                                 // N
    int*  pos    = startv + N;                              // N
    int*  part   = pos + N;                                 // 256
    int2* ew     = (int2*)(part + 256);                     // E + 4N (padded CSR)

    const int nbN = (N + 255) / 256;
    const int nbE = (E + 255) / 256;

    prep<<<(N * H / 8 + 255) / 256, 256, 0, stream>>>(z, Wmsg, Wupd, Az, WmT, WuT, deg, ZSD, N);

    gemm_zszd_mfma<<<784, 256, 0, stream>>>(Az, WmT, ZSD, N, ntiles);

    hist_dst<<<nbE, 256, 0, stream>>>(dst, deg, E);
    scan_a<<<nbN, 256, 0, stream>>>(deg, startv, part, N);
    scan_b<<<1, 256, 0, stream>>>(part, nbN);
    scan_c<<<nbN, 256, 0, stream>>>(startv, pos, part, deg, ew, N);
    scatter_edges<<<nbE, 256, 0, stream>>>(src, dst, wgt, pos, ew, E);

    aggregate<<<(N + 3) / 4, 256, 0, stream>>>(
        ZSD, Az, bmsg, Wmsg + (size_t)256 * H, startv, deg, ew, N);

    gemm_upd_mfma<<<784, 256, 0, stream>>>(Az, WuT, bupd, out, N, ntiles);
}